// Round 7
// baseline (2039.862 us; speedup 1.0000x reference)
//
#include <hip/hip_runtime.h>
#include <math.h>

#define TT 8
#define NNODES 20000
#define NEDGES 320000
#define FDIM 128
#define HDIM 128
#define BGR 64
#define NCLS 16
#define GR 128   // gemm rows per block
#define ITEMS (NEDGES + NNODES)   // edges + self-loops
#define CPT 64                    // chunks (blocks) per timestep for k_agg
#define IPB ((ITEMS + CPT - 1) / CPT)

__device__ __forceinline__ float lrelu(float x) { return fmaxf(x, 0.2f * x); }
__device__ __forceinline__ float sigmoidf(float x) { return 1.0f / (1.0f + __expf(-x)); }
__device__ __forceinline__ float tanh_fast(float x) {
  return 1.0f - 2.0f / (__expf(2.0f * x) + 1.0f);
}
__device__ __forceinline__ unsigned short f2bf(float f) {   // RNE
  unsigned int u = __float_as_uint(f);
  unsigned int r = (u + 0x7fff + ((u >> 16) & 1)) >> 16;
  return (unsigned short)r;
}
__device__ __forceinline__ float bf_lo(unsigned int u) { return __uint_as_float(u << 16); }
__device__ __forceinline__ float bf_hi(unsigned int u) { return __uint_as_float(u & 0xffff0000u); }

// ---------------- GEMM: h = x @ W, h stored bf16 PAIR-PERMUTED: uint slot d
// packs (h[d], h[d+64]). Epilogue: as=h@att_src, ad=h@att_dst, denom=exp(lrelu(as+ad)).
__global__ __launch_bounds__(256) void k_gemm(
    const float* __restrict__ x, const float* __restrict__ W,
    const float* __restrict__ att_s, const float* __restrict__ att_d,
    unsigned int* __restrict__ hbp, float* __restrict__ as_, float* __restrict__ ad_,
    float* __restrict__ denom) {
  __shared__ float xsT[32][GR + 4];   // [k][row]
  __shared__ float ws[32][HDIM];      // [k][col]
  __shared__ float asl[GR], adl[GR];
  __shared__ float atts[HDIM], attd[HDIM];
  const int tid = threadIdx.x;
  const int row0 = blockIdx.x * GR;
  if (tid < GR) { asl[tid] = 0.f; adl[tid] = 0.f; }
  if (tid < 128) { atts[tid] = att_s[tid]; attd[tid] = att_d[tid]; }
  const int ty = tid >> 4;   // 0..15 -> 8 rows each
  const int tx = tid & 15;   // cols: {tx*4..tx*4+3} and {64+tx*4..64+tx*4+3}
  float acc[8][8] = {};
  for (int kb = 0; kb < 4; ++kb) {
    __syncthreads();
    #pragma unroll
    for (int p = 0; p < 4; ++p) {   // x tile: 128 rows x 32 k, transposed store
      int idx = tid + p * 256;
      int r = idx >> 3, k4 = idx & 7;
      float4 v = *(const float4*)(x + (size_t)(row0 + r) * FDIM + kb * 32 + k4 * 4);
      xsT[k4 * 4 + 0][r] = v.x; xsT[k4 * 4 + 1][r] = v.y;
      xsT[k4 * 4 + 2][r] = v.z; xsT[k4 * 4 + 3][r] = v.w;
    }
    #pragma unroll
    for (int p = 0; p < 4; ++p) {   // W tile
      int kr = (tid >> 5) + p * 8;
      int c4 = (tid & 31) * 4;
      *(float4*)(&ws[kr][c4]) = *(const float4*)(W + (size_t)(kb * 32 + kr) * HDIM + c4);
    }
    __syncthreads();
    #pragma unroll
    for (int k = 0; k < 32; ++k) {
      float a[8], bb[8];
      *(float4*)&a[0]  = *(const float4*)(&xsT[k][ty * 8]);
      *(float4*)&a[4]  = *(const float4*)(&xsT[k][ty * 8 + 4]);
      *(float4*)&bb[0] = *(const float4*)(&ws[k][tx * 4]);
      *(float4*)&bb[4] = *(const float4*)(&ws[k][64 + tx * 4]);
      #pragma unroll
      for (int i = 0; i < 8; ++i)
        #pragma unroll
        for (int j = 0; j < 8; ++j)
          acc[i][j] += a[i] * bb[j];
    }
  }
  float av[8], dv[8];
  *(float4*)&av[0] = *(const float4*)(&atts[tx * 4]);
  *(float4*)&av[4] = *(const float4*)(&atts[64 + tx * 4]);
  *(float4*)&dv[0] = *(const float4*)(&attd[tx * 4]);
  *(float4*)&dv[4] = *(const float4*)(&attd[64 + tx * 4]);
  #pragma unroll
  for (int i = 0; i < 8; ++i) {
    int row = row0 + ty * 8 + i;
    float ps = 0.f, pd = 0.f;
    #pragma unroll
    for (int j = 0; j < 8; ++j) { ps += acc[i][j] * av[j]; pd += acc[i][j] * dv[j]; }
    uint4 pk;   // slot tx*4+q packs (col tx*4+q, col 64+tx*4+q)
    pk.x = (unsigned int)f2bf(acc[i][0]) | ((unsigned int)f2bf(acc[i][4]) << 16);
    pk.y = (unsigned int)f2bf(acc[i][1]) | ((unsigned int)f2bf(acc[i][5]) << 16);
    pk.z = (unsigned int)f2bf(acc[i][2]) | ((unsigned int)f2bf(acc[i][6]) << 16);
    pk.w = (unsigned int)f2bf(acc[i][3]) | ((unsigned int)f2bf(acc[i][7]) << 16);
    *(uint4*)(hbp + (size_t)row * 64 + tx * 4) = pk;
    atomicAdd(&asl[ty * 8 + i], ps);
    atomicAdd(&adl[ty * 8 + i], pd);
  }
  __syncthreads();
  if (tid < GR) {
    float a = asl[tid], d = adl[tid];
    as_[row0 + tid] = a;
    ad_[row0 + tid] = d;
    denom[row0 + tid] = __expf(lrelu(a + d));   // self-loop term seeds denominator
  }
}

// ---------------- edge-parallel softmax denominator
__global__ void k_denom(const int* __restrict__ ei, const float* __restrict__ as_,
                        const float* __restrict__ ad_, float* __restrict__ denom) {
  int gidx = blockIdx.x * 256 + threadIdx.x;   // over T*E (exact multiple)
  int t = gidx / NEDGES, e = gidx - t * NEDGES;
  int src = ei[(size_t)t * 2 * NEDGES + e];
  int dst = ei[(size_t)t * 2 * NEDGES + NEDGES + e];
  float w = __expf(lrelu(as_[t * NNODES + src] + ad_[t * NNODES + dst]));
  atomicAdd(&denom[t * NNODES + dst], w);
}

__global__ void k_dinv(const float* __restrict__ denom, float* __restrict__ dinv) {
  int i = blockIdx.x * 256 + threadIdx.x;   // T*N exact multiple
  dinv[i] = 1.0f / denom[i];
}

// ---------------- batch segment starts (batch is sorted)
__global__ void k_starts(const int* __restrict__ batch, int* __restrict__ starts) {
  int n = blockIdx.x * 256 + threadIdx.x;
  if (n >= NNODES) return;
  int b = batch[n];
  if (n == 0) { for (int bb = 0; bb <= b; ++bb) starts[bb] = 0; }
  else { int pb = batch[n - 1]; for (int bb = pb + 1; bb <= b; ++bb) starts[bb] = n; }
  if (n == NNODES - 1) { for (int bb = b + 1; bb <= BGR; ++bb) starts[bb] = NNODES; }
}

// ---------------- edge-parallel aggregate+pool: LDS-privatized pooled[64][128].
// Items 0..E-1 are edges, E..E+N-1 are self-loops. Lane l owns dims (l, l+64)
// via the pair-permuted h layout -> both ds_adds hit bank l%32 (2 lanes/bank, free).
__global__ __launch_bounds__(256) void k_agg(
    const unsigned int* __restrict__ hbp, const float* __restrict__ as_,
    const float* __restrict__ ad_, const float* __restrict__ dinv,
    const int* __restrict__ ei, const int* __restrict__ batch,
    float* __restrict__ pooled) {
  __shared__ float plds[BGR * HDIM];      // 32 KB
  __shared__ uint4 sew[4][64];            // (src, w_scaled, batch, pad)
  const int tid = threadIdx.x;
  const int w = tid >> 6, lane = tid & 63;
  const int t = blockIdx.x / CPT;
  const int chunk = blockIdx.x - t * CPT;
  const int i0 = chunk * IPB;
  const int i1 = min(i0 + IPB, ITEMS);
  #pragma unroll
  for (int i = tid; i < BGR * HDIM; i += 256) plds[i] = 0.f;
  __syncthreads();

  const int* eis = ei + (size_t)t * 2 * NEDGES;
  const float* asb = as_ + (size_t)t * NNODES;
  const float* adb = ad_ + (size_t)t * NNODES;
  const float* dvb = dinv + (size_t)t * NNODES;
  const unsigned int* hball = hbp + (size_t)t * NNODES * 64;

  for (int base = i0 + w * 64; base < i1; base += 256) {
    const int c = min(64, i1 - base);
    if (lane < c) {
      int i = base + lane;
      int src, dst;
      if (i < NEDGES) { src = eis[i]; dst = eis[NEDGES + i]; }
      else { src = i - NEDGES; dst = src; }
      float wv = __expf(lrelu(asb[src] + adb[dst])) * dvb[dst];
      sew[w][lane] = make_uint4((unsigned int)src, __float_as_uint(wv),
                                (unsigned int)batch[dst], 0u);
    }
    // same-wave LDS produce->consume (program order within wave)
    #pragma unroll 4
    for (int j = 0; j < c; ++j) {
      uint4 m = sew[w][j];
      float wgt = __uint_as_float(m.y);
      unsigned int u = hball[(size_t)m.x * 64 + lane];
      atomicAdd(&plds[m.z * 128 + lane], wgt * bf_lo(u));
      atomicAdd(&plds[m.z * 128 + 64 + lane], wgt * bf_hi(u));
    }
  }
  __syncthreads();
  float* pg = pooled + (size_t)t * BGR * HDIM;
  #pragma unroll
  for (int i = tid; i < BGR * HDIM; i += 256) {
    float v = plds[i];
    if (v != 0.f) atomicAdd(&pg[i], v);
  }
}

// ---------------- LSTM over T + fused FC (one block per batch row b)
// W_hh staged once into LDS as packed bf16 pairs (stride-65 rows: conflict-free).
// gat_bias folded here: mean(aggr + bias) = mean(aggr) + bias.
__global__ __launch_bounds__(512) void k_lstm_fc(
    const float* __restrict__ pooled, const int* __restrict__ starts,
    const float* __restrict__ gat_bias,
    const float* __restrict__ W_ih, const float* __restrict__ W_hh,
    const float* __restrict__ b_ih, const float* __restrict__ b_hh,
    const float* __restrict__ z, const float* __restrict__ fc_W,
    const float* __restrict__ fc_b, float* __restrict__ out) {
  const int b = blockIdx.x;
  const int g = threadIdx.x;   // gate index 0..511 (i,f,g,o blocks of 128)
  __shared__ unsigned int wpk[512 * 65];   // 133.1 KB packed bf16 W_hh
  __shared__ float hv[128], cv[128], part[512];
  __shared__ float pool8[TT][128];
  __shared__ float fcp[16][17];

  #pragma unroll 2
  for (int it = 0; it < 64; ++it) {
    int i = g + it * 512;
    int gr = i >> 6, j = i & 63;
    float2 wv = *(const float2*)(W_hh + (size_t)gr * HDIM + j * 2);
    wpk[gr * 65 + j] = (unsigned int)f2bf(wv.x) | ((unsigned int)f2bf(wv.y) << 16);
  }

  const int cntb = starts[b + 1] - starts[b];
  const float invc = 1.0f / (float)max(cntb, 1);
  #pragma unroll
  for (int i = 0; i < 2; ++i) {
    int idx = g + i * 512;
    int t = idx >> 7, k = idx & 127;
    pool8[t][k] = pooled[((size_t)t * BGR + b) * HDIM + k] * invc + gat_bias[k];
  }
  if (g < 128) { hv[g] = 0.f; cv[g] = 0.f; }
  __syncthreads();

  float gx[8] = {};
  {
    const float4* wi = (const float4*)(W_ih + (size_t)g * HDIM);
    #pragma unroll 2
    for (int k4 = 0; k4 < 32; ++k4) {
      float4 wv = wi[k4];
      #pragma unroll
      for (int t = 0; t < TT; ++t) {
        float4 p = *(const float4*)(&pool8[t][k4 * 4]);
        gx[t] += wv.x * p.x + wv.y * p.y + wv.z * p.z + wv.w * p.w;
      }
    }
  }
  const float bsum = b_ih[g] + b_hh[g];
  const unsigned int* wr = &wpk[g * 65];
  const float4* hv4 = (const float4*)hv;
  #pragma unroll
  for (int t = 0; t < TT; ++t) {
    float s = gx[t] + bsum;
    #pragma unroll 8
    for (int j2 = 0; j2 < 32; ++j2) {
      unsigned int w0 = wr[2 * j2], w1 = wr[2 * j2 + 1];
      float4 hh = hv4[j2];
      s += bf_lo(w0) * hh.x + bf_hi(w0) * hh.y + bf_lo(w1) * hh.z + bf_hi(w1) * hh.w;
    }
    part[g] = s;
    __syncthreads();
    if (g < 128) {
      float ig = sigmoidf(part[g]);
      float fg = sigmoidf(part[128 + g]);
      float gc = tanh_fast(part[256 + g]);
      float og = sigmoidf(part[384 + g]);
      float c = fg * cv[g] + ig * gc;
      cv[g] = c;
      hv[g] = og * tanh_fast(c);
    }
    __syncthreads();
  }
  if (g < 256) {
    const int c = g >> 4, kp = g & 15;
    float s = 0.f;
    for (int k = kp * 16; k < kp * 16 + 16; ++k) {
      float v = (k < 128) ? hv[k] : z[(size_t)b * HDIM + (k - 128)];
      s += v * fc_W[(size_t)c * 256 + k];
    }
    fcp[c][kp] = s;
  }
  __syncthreads();
  if (g < 16) {
    float r = fc_b[g];
    #pragma unroll
    for (int k = 0; k < 16; ++k) r += fcp[g][k];
    out[(size_t)b * NCLS + g] = r;
  }
}

extern "C" void kernel_launch(void* const* d_in, const int* in_sizes, int n_in,
                              void* d_out, int out_size, void* d_ws, size_t ws_size,
                              hipStream_t stream) {
  const float* x       = (const float*)d_in[0];
  const int*   ei      = (const int*)d_in[1];
  const int*   batch   = (const int*)d_in[2];
  const float* z       = (const float*)d_in[3];
  const float* gat_W   = (const float*)d_in[4];
  const float* att_src = (const float*)d_in[5];
  const float* att_dst = (const float*)d_in[6];
  const float* gat_bias= (const float*)d_in[7];
  const float* W_ih    = (const float*)d_in[8];
  const float* W_hh    = (const float*)d_in[9];
  const float* b_ih    = (const float*)d_in[10];
  const float* b_hh    = (const float*)d_in[11];
  const float* fc_W    = (const float*)d_in[12];
  const float* fc_b    = (const float*)d_in[13];
  float* out = (float*)d_out;

  char* ws = (char*)d_ws;
  size_t off = 0;
  auto alloc = [&](size_t bytes) {
    void* p = (void*)(ws + off);
    off += (bytes + 255) & ~(size_t)255;
    return p;
  };
  unsigned int* hbp = (unsigned int*)alloc((size_t)TT * NNODES * 64 * 4);  // 41 MB pair-packed bf16
  float* as_    = (float*)alloc((size_t)TT * NNODES * 4);
  float* ad_    = (float*)alloc((size_t)TT * NNODES * 4);
  float* denom  = (float*)alloc((size_t)TT * NNODES * 4);
  float* dinv   = (float*)alloc((size_t)TT * NNODES * 4);
  int*   starts = (int*)alloc((BGR + 1) * 4);
  float* pooled = (float*)alloc((size_t)TT * BGR * HDIM * 4);
  (void)ws_size; (void)in_sizes; (void)n_in; (void)out_size;

  hipMemsetAsync(pooled, 0, (size_t)TT * BGR * HDIM * 4, stream);

  k_gemm<<<(TT * NNODES) / GR, 256, 0, stream>>>(x, gat_W, att_src, att_dst, hbp, as_, ad_, denom);
  k_denom<<<(TT * NEDGES) / 256, 256, 0, stream>>>(ei, as_, ad_, denom);
  k_dinv<<<(TT * NNODES) / 256, 256, 0, stream>>>(denom, dinv);
  k_starts<<<(NNODES + 255) / 256, 256, 0, stream>>>(batch, starts);
  k_agg<<<TT * CPT, 256, 0, stream>>>(hbp, as_, ad_, dinv, ei, batch, pooled);
  k_lstm_fc<<<BGR, 512, 0, stream>>>(pooled, starts, gat_bias, W_ih, W_hh, b_ih, b_hh, z, fc_W, fc_b, out);
}

// Round 8
// 571.082 us; speedup vs baseline: 3.5719x; 3.5719x over previous
//
#include <hip/hip_runtime.h>
#include <math.h>

#define TT 8
#define NNODES 20000
#define NEDGES 320000
#define FDIM 128
#define HDIM 128
#define BGR 64
#define NCLS 16
#define GR 128   // gemm rows per block

__device__ __forceinline__ float lrelu(float x) { return fmaxf(x, 0.2f * x); }
__device__ __forceinline__ float sigmoidf(float x) { return 1.0f / (1.0f + __expf(-x)); }
__device__ __forceinline__ float tanh_fast(float x) {
  return 1.0f - 2.0f / (__expf(2.0f * x) + 1.0f);
}
__device__ __forceinline__ unsigned short f2bf(float f) {   // RNE
  unsigned int u = __float_as_uint(f);
  unsigned int r = (u + 0x7fff + ((u >> 16) & 1)) >> 16;
  return (unsigned short)r;
}
__device__ __forceinline__ float bf_lo(unsigned int u) { return __uint_as_float(u << 16); }
__device__ __forceinline__ float bf_hi(unsigned int u) { return __uint_as_float(u & 0xffff0000u); }

// ---------------- GEMM: h = x @ W (h stored bf16), epilogue: as=h@att_src, ad=h@att_dst
// 128x128 tile per block, 256 threads, 8x8 acc per thread.
__global__ __launch_bounds__(256) void k_gemm(
    const float* __restrict__ x, const float* __restrict__ W,
    const float* __restrict__ att_s, const float* __restrict__ att_d,
    unsigned short* __restrict__ hb, float* __restrict__ as_, float* __restrict__ ad_) {
  __shared__ float xsT[32][GR + 4];   // [k][row]
  __shared__ float ws[32][HDIM];      // [k][col]
  __shared__ float asl[GR], adl[GR];
  __shared__ float atts[HDIM], attd[HDIM];
  const int tid = threadIdx.x;
  const int row0 = blockIdx.x * GR;
  if (tid < GR) { asl[tid] = 0.f; adl[tid] = 0.f; }
  if (tid < 128) { atts[tid] = att_s[tid]; attd[tid] = att_d[tid]; }
  const int ty = tid >> 4;   // 0..15 -> 8 rows each
  const int tx = tid & 15;   // 0..15 -> 8 cols each
  float acc[8][8] = {};
  for (int kb = 0; kb < 4; ++kb) {
    __syncthreads();
    #pragma unroll
    for (int p = 0; p < 4; ++p) {   // x tile: 128 rows x 32 k, transposed store
      int idx = tid + p * 256;
      int r = idx >> 3, k4 = idx & 7;
      float4 v = *(const float4*)(x + (size_t)(row0 + r) * FDIM + kb * 32 + k4 * 4);
      xsT[k4 * 4 + 0][r] = v.x; xsT[k4 * 4 + 1][r] = v.y;
      xsT[k4 * 4 + 2][r] = v.z; xsT[k4 * 4 + 3][r] = v.w;
    }
    #pragma unroll
    for (int p = 0; p < 4; ++p) {   // W tile
      int kr = (tid >> 5) + p * 8;
      int c4 = (tid & 31) * 4;
      *(float4*)(&ws[kr][c4]) = *(const float4*)(W + (size_t)(kb * 32 + kr) * HDIM + c4);
    }
    __syncthreads();
    #pragma unroll
    for (int k = 0; k < 32; ++k) {
      float a[8], bb[8];
      *(float4*)&a[0]  = *(const float4*)(&xsT[k][ty * 8]);
      *(float4*)&a[4]  = *(const float4*)(&xsT[k][ty * 8 + 4]);
      *(float4*)&bb[0] = *(const float4*)(&ws[k][tx * 8]);
      *(float4*)&bb[4] = *(const float4*)(&ws[k][tx * 8 + 4]);
      #pragma unroll
      for (int i = 0; i < 8; ++i)
        #pragma unroll
        for (int j = 0; j < 8; ++j)
          acc[i][j] += a[i] * bb[j];
    }
  }
  float av[8], dv[8];
  *(float4*)&av[0] = *(const float4*)(&atts[tx * 8]);
  *(float4*)&av[4] = *(const float4*)(&atts[tx * 8 + 4]);
  *(float4*)&dv[0] = *(const float4*)(&attd[tx * 8]);
  *(float4*)&dv[4] = *(const float4*)(&attd[tx * 8 + 4]);
  #pragma unroll
  for (int i = 0; i < 8; ++i) {
    int row = row0 + ty * 8 + i;
    float ps = 0.f, pd = 0.f;
    #pragma unroll
    for (int j = 0; j < 8; ++j) { ps += acc[i][j] * av[j]; pd += acc[i][j] * dv[j]; }
    uint4 pk;
    pk.x = (unsigned int)f2bf(acc[i][0]) | ((unsigned int)f2bf(acc[i][1]) << 16);
    pk.y = (unsigned int)f2bf(acc[i][2]) | ((unsigned int)f2bf(acc[i][3]) << 16);
    pk.z = (unsigned int)f2bf(acc[i][4]) | ((unsigned int)f2bf(acc[i][5]) << 16);
    pk.w = (unsigned int)f2bf(acc[i][6]) | ((unsigned int)f2bf(acc[i][7]) << 16);
    *(uint4*)(hb + (size_t)row * HDIM + tx * 8) = pk;
    atomicAdd(&asl[ty * 8 + i], ps);
    atomicAdd(&adl[ty * 8 + i], pd);
  }
  __syncthreads();
  if (tid < GR) { as_[row0 + tid] = asl[tid]; ad_[row0 + tid] = adl[tid]; }
}

// ---------------- CSR build
__global__ void k_hist(const int* __restrict__ ei, int* __restrict__ cnt) {
  int g = blockIdx.x * 256 + threadIdx.x;
  int t = g / NEDGES, e = g - t * NEDGES;
  int dst = ei[(size_t)t * 2 * NEDGES + NEDGES + e];
  atomicAdd(&cnt[t * NNODES + dst], 1);
}

__global__ __launch_bounds__(256) void k_scan(const int* __restrict__ cnt, int* __restrict__ offs) {
  const int t = blockIdx.x;
  const int tid = threadIdx.x;
  const int SPAN = 79;
  __shared__ int sums[256];
  int lo = tid * SPAN, hi = min(lo + SPAN, NNODES);
  int s = 0;
  for (int i = lo; i < hi; ++i) s += cnt[t * NNODES + i];
  sums[tid] = s;
  __syncthreads();
  for (int off = 1; off < 256; off <<= 1) {
    int add = (tid >= off) ? sums[tid - off] : 0;
    __syncthreads();
    sums[tid] += add;
    __syncthreads();
  }
  int run = sums[tid] - s;
  for (int i = lo; i < hi; ++i) { offs[t * NNODES + i] = run; run += cnt[t * NNODES + i]; }
}

// csr entries are ushort (src < 20000 < 65536): halves buffer + write-line traffic.
__global__ void k_scatter(const int* __restrict__ ei, int* __restrict__ offs,
                          unsigned short* __restrict__ csr) {
  int g = blockIdx.x * 256 + threadIdx.x;
  int t = g / NEDGES, e = g - t * NEDGES;
  int src = ei[(size_t)t * 2 * NEDGES + e];
  int dst = ei[(size_t)t * 2 * NEDGES + NEDGES + e];
  int pos = atomicAdd(&offs[t * NNODES + dst], 1);
  __builtin_nontemporal_store((unsigned short)src, &csr[(size_t)t * NEDGES + pos]);
}

// ---------------- batch segment starts (batch is sorted)
__global__ void k_starts(const int* __restrict__ batch, int* __restrict__ starts) {
  int n = blockIdx.x * 256 + threadIdx.x;
  if (n >= NNODES) return;
  int b = batch[n];
  if (n == 0) { for (int bb = 0; bb <= b; ++bb) starts[bb] = 0; }
  else { int pb = batch[n - 1]; for (int bb = pb + 1; bb <= b; ++bb) starts[bb] = n; }
  if (n == NNODES - 1) { for (int bb = b + 1; bb <= BGR; ++bb) starts[bb] = NNODES; }
}

// ---------------- per-node softmax-aggregate (wave per node, split-wave bf16 gather)
__global__ __launch_bounds__(256) void k_aggr(
    const unsigned short* __restrict__ hb, const float* __restrict__ as_, const float* __restrict__ ad_,
    const int* __restrict__ cnt, const int* __restrict__ offs, const unsigned short* __restrict__ csr,
    const int* __restrict__ batch, const float* __restrict__ bias,
    float* __restrict__ pooled) {
  __shared__ float pacc[4][128];
  __shared__ uint2 sew[4][64];      // (src, weight-bits) packed
  __shared__ int wb[4];
  const int tid = threadIdx.x;
  const int w = tid >> 6, lane = tid & 63;
  const int half = lane >> 5, l5 = lane & 31;
  const int blk = blockIdx.x;
  const int t = blk / (NNODES / 4);
  const int n = (blk - t * (NNODES / 4)) * 4 + w;
  const int tn = t * NNODES + n;
  const int deg = cnt[tn];
  const int end = offs[tn];          // after scatter, offs holds segment end
  const int start = end - deg;
  const float adn = ad_[tn];
  const float wself = __expf(lrelu(as_[tn] + adn));
  const unsigned short* ecsr = csr + (size_t)t * NEDGES;
  const float* asb = as_ + (size_t)t * NNODES;
  const unsigned short* hbase = hb + (size_t)t * NNODES * HDIM;

  // self term: even half only (lane dims l5*4 .. l5*4+3)
  float acc0, acc1, acc2, acc3;
  if (half == 0) {
    uint2 u = *(const uint2*)(hbase + (size_t)n * HDIM + l5 * 4);
    acc0 = wself * bf_lo(u.x); acc1 = wself * bf_hi(u.x);
    acc2 = wself * bf_lo(u.y); acc3 = wself * bf_hi(u.y);
  } else { acc0 = acc1 = acc2 = acc3 = 0.f; }
  float sp = 0.f;

  for (int base = start; base < end; base += 64) {
    const int c = min(64, end - base);
    {
      int s = 0; float wv = 0.f;
      if (lane < c) { s = ecsr[base + lane]; wv = __expf(lrelu(asb[s] + adn)); }
      sew[w][lane] = make_uint2((unsigned int)s, __float_as_uint(wv));
      sp += wv;
    }
    // same-wave LDS produce->consume: program order within wave
    const int cp = (c + 1) & ~1;       // pad to pair (pad weight = 0)
    #pragma unroll 4
    for (int j = 0; j < cp; j += 2) {
      uint2 ew = sew[w][j + half];     // half 0 -> even edge, half 1 -> odd edge
      float wgt = __uint_as_float(ew.y);
      uint2 u = *(const uint2*)(hbase + (size_t)ew.x * HDIM + l5 * 4);
      acc0 += wgt * bf_lo(u.x); acc1 += wgt * bf_hi(u.x);
      acc2 += wgt * bf_lo(u.y); acc3 += wgt * bf_hi(u.y);
    }
  }
  #pragma unroll
  for (int o = 32; o > 0; o >>= 1) sp += __shfl_xor(sp, o);
  const float inv = 1.0f / (sp + wself);
  acc0 += __shfl_xor(acc0, 32);
  acc1 += __shfl_xor(acc1, 32);
  acc2 += __shfl_xor(acc2, 32);
  acc3 += __shfl_xor(acc3, 32);
  if (half == 0) {
    float4 bv = *(const float4*)(bias + l5 * 4);
    pacc[w][l5 * 4 + 0] = acc0 * inv + bv.x;
    pacc[w][l5 * 4 + 1] = acc1 * inv + bv.y;
    pacc[w][l5 * 4 + 2] = acc2 * inv + bv.z;
    pacc[w][l5 * 4 + 3] = acc3 * inv + bv.w;
  }
  if (lane == 0) wb[w] = batch[n];
  __syncthreads();
  // sorted-adjacent merge of the 4 node slots
  if (tid < 128 && wb[3] == wb[2]) pacc[2][tid] += pacc[3][tid];
  __syncthreads();
  if (tid < 128 && wb[2] == wb[1]) pacc[1][tid] += pacc[2][tid];
  __syncthreads();
  if (tid < 128 && wb[1] == wb[0]) pacc[0][tid] += pacc[1][tid];
  __syncthreads();
  #pragma unroll
  for (int it = tid; it < 512; it += 256) {
    int ww = it >> 7, d = it & 127;
    bool root = (ww == 0) || (wb[ww] != wb[ww - 1]);
    if (root) atomicAdd(&pooled[((size_t)t * BGR + wb[ww]) * HDIM + d], pacc[ww][d]);
  }
}

// ---------------- LSTM over T + fused FC (one block per batch row b)
// W_hh staged ONCE into LDS as packed bf16 pairs, row stride 65 uints
// (2 lanes/bank on write and read = conflict-free). No weight register arrays.
__global__ __launch_bounds__(512) void k_lstm_fc(
    const float* __restrict__ pooled, const int* __restrict__ starts,
    const float* __restrict__ W_ih, const float* __restrict__ W_hh,
    const float* __restrict__ b_ih, const float* __restrict__ b_hh,
    const float* __restrict__ z, const float* __restrict__ fc_W,
    const float* __restrict__ fc_b, float* __restrict__ out) {
  const int b = blockIdx.x;
  const int g = threadIdx.x;   // gate index 0..511 (i,f,g,o blocks of 128)
  __shared__ unsigned int wpk[512 * 65];   // 133.1 KB packed bf16 W_hh
  __shared__ float hv[128], cv[128], part[512];
  __shared__ float pool8[TT][128];
  __shared__ float fcp[16][17];

  #pragma unroll 2
  for (int it = 0; it < 64; ++it) {
    int i = g + it * 512;
    int gr = i >> 6, j = i & 63;
    float2 wv = *(const float2*)(W_hh + (size_t)gr * HDIM + j * 2);
    wpk[gr * 65 + j] = (unsigned int)f2bf(wv.x) | ((unsigned int)f2bf(wv.y) << 16);
  }

  const int cntb = starts[b + 1] - starts[b];
  const float invc = 1.0f / (float)max(cntb, 1);
  #pragma unroll
  for (int i = 0; i < 2; ++i) {
    int idx = g + i * 512;
    int t = idx >> 7, k = idx & 127;
    pool8[t][k] = pooled[((size_t)t * BGR + b) * HDIM + k] * invc;
  }
  if (g < 128) { hv[g] = 0.f; cv[g] = 0.f; }
  __syncthreads();

  float gx[8] = {};
  {
    const float4* wi = (const float4*)(W_ih + (size_t)g * HDIM);
    #pragma unroll 2
    for (int k4 = 0; k4 < 32; ++k4) {
      float4 wv = wi[k4];
      #pragma unroll
      for (int t = 0; t < TT; ++t) {
        float4 p = *(const float4*)(&pool8[t][k4 * 4]);
        gx[t] += wv.x * p.x + wv.y * p.y + wv.z * p.z + wv.w * p.w;
      }
    }
  }
  const float bsum = b_ih[g] + b_hh[g];
  const unsigned int* wr = &wpk[g * 65];
  const float4* hv4 = (const float4*)hv;
  #pragma unroll
  for (int t = 0; t < TT; ++t) {
    float s = gx[t] + bsum;
    #pragma unroll 8
    for (int j2 = 0; j2 < 32; ++j2) {
      unsigned int w0 = wr[2 * j2], w1 = wr[2 * j2 + 1];
      float4 hh = hv4[j2];
      s += bf_lo(w0) * hh.x + bf_hi(w0) * hh.y + bf_lo(w1) * hh.z + bf_hi(w1) * hh.w;
    }
    part[g] = s;
    __syncthreads();
    if (g < 128) {
      float ig = sigmoidf(part[g]);
      float fg = sigmoidf(part[128 + g]);
      float gc = tanh_fast(part[256 + g]);
      float og = sigmoidf(part[384 + g]);
      float c = fg * cv[g] + ig * gc;
      cv[g] = c;
      hv[g] = og * tanh_fast(c);
    }
    __syncthreads();
  }
  if (g < 256) {
    const int c = g >> 4, kp = g & 15;
    float s = 0.f;
    for (int k = kp * 16; k < kp * 16 + 16; ++k) {
      float v = (k < 128) ? hv[k] : z[(size_t)b * HDIM + (k - 128)];
      s += v * fc_W[(size_t)c * 256 + k];
    }
    fcp[c][kp] = s;
  }
  __syncthreads();
  if (g < 16) {
    float r = fc_b[g];
    #pragma unroll
    for (int k = 0; k < 16; ++k) r += fcp[g][k];
    out[(size_t)b * NCLS + g] = r;
  }
}

extern "C" void kernel_launch(void* const* d_in, const int* in_sizes, int n_in,
                              void* d_out, int out_size, void* d_ws, size_t ws_size,
                              hipStream_t stream) {
  const float* x       = (const float*)d_in[0];
  const int*   ei      = (const int*)d_in[1];
  const int*   batch   = (const int*)d_in[2];
  const float* z       = (const float*)d_in[3];
  const float* gat_W   = (const float*)d_in[4];
  const float* att_src = (const float*)d_in[5];
  const float* att_dst = (const float*)d_in[6];
  const float* gat_bias= (const float*)d_in[7];
  const float* W_ih    = (const float*)d_in[8];
  const float* W_hh    = (const float*)d_in[9];
  const float* b_ih    = (const float*)d_in[10];
  const float* b_hh    = (const float*)d_in[11];
  const float* fc_W    = (const float*)d_in[12];
  const float* fc_b    = (const float*)d_in[13];
  float* out = (float*)d_out;

  char* ws = (char*)d_ws;
  size_t off = 0;
  auto alloc = [&](size_t bytes) {
    void* p = (void*)(ws + off);
    off += (bytes + 255) & ~(size_t)255;
    return p;
  };
  unsigned short* hbuf = (unsigned short*)alloc((size_t)TT * NNODES * HDIM * 2);  // 41 MB bf16
  float* as_    = (float*)alloc((size_t)TT * NNODES * 4);
  float* ad_    = (float*)alloc((size_t)TT * NNODES * 4);
  int*   cnt    = (int*)alloc((size_t)TT * NNODES * 4);
  int*   offs   = (int*)alloc((size_t)TT * NNODES * 4);
  unsigned short* csr = (unsigned short*)alloc((size_t)TT * NEDGES * 2);   // 5.12 MB
  int*   starts = (int*)alloc((BGR + 1) * 4);
  float* pooled = (float*)alloc((size_t)TT * BGR * HDIM * 4);
  (void)ws_size; (void)in_sizes; (void)n_in; (void)out_size;

  hipMemsetAsync(cnt, 0, (size_t)TT * NNODES * 4, stream);
  hipMemsetAsync(pooled, 0, (size_t)TT * BGR * HDIM * 4, stream);

  k_gemm<<<(TT * NNODES) / GR, 256, 0, stream>>>(x, gat_W, att_src, att_dst, hbuf, as_, ad_);
  k_hist<<<(TT * NEDGES) / 256, 256, 0, stream>>>(ei, cnt);
  k_scan<<<TT, 256, 0, stream>>>(cnt, offs);
  k_scatter<<<(TT * NEDGES) / 256, 256, 0, stream>>>(ei, offs, csr);
  k_starts<<<(NNODES + 255) / 256, 256, 0, stream>>>(batch, starts);
  k_aggr<<<TT * (NNODES / 4), 256, 0, stream>>>(hbuf, as_, ad_, cnt, offs, csr, batch, gat_bias, pooled);
  k_lstm_fc<<<BGR, 512, 0, stream>>>(pooled, starts, W_ih, W_hh, b_ih, b_hh, z, fc_W, fc_b, out);
}

// Round 9
// 492.011 us; speedup vs baseline: 4.1460x; 1.1607x over previous
//
#include <hip/hip_runtime.h>
#include <math.h>

#define TT 8
#define NNODES 20000
#define NEDGES 320000
#define FDIM 128
#define HDIM 128
#define BGR 64
#define NCLS 16
#define GR 128   // gemm rows per block
#define NCH 32   // K-chunks per timestep for k_pgemm
#define KC 640   // nodes per chunk (multiple of 32; 32*640 = 20480 >= 20000)

__device__ __forceinline__ float lrelu(float x) { return fmaxf(x, 0.2f * x); }
__device__ __forceinline__ float sigmoidf(float x) { return 1.0f / (1.0f + __expf(-x)); }
__device__ __forceinline__ float tanh_fast(float x) {
  return 1.0f - 2.0f / (__expf(2.0f * x) + 1.0f);
}
__device__ __forceinline__ unsigned short f2bf(float f) {   // RNE
  unsigned int u = __float_as_uint(f);
  unsigned int r = (u + 0x7fff + ((u >> 16) & 1)) >> 16;
  return (unsigned short)r;
}
__device__ __forceinline__ float bf_lo(unsigned int u) { return __uint_as_float(u << 16); }
__device__ __forceinline__ float bf_hi(unsigned int u) { return __uint_as_float(u & 0xffff0000u); }

// ---------------- GEMM: h = x @ W (h stored bf16), epilogue: as, ad, denom seed (self term)
__global__ __launch_bounds__(256) void k_gemm(
    const float* __restrict__ x, const float* __restrict__ W,
    const float* __restrict__ att_s, const float* __restrict__ att_d,
    unsigned short* __restrict__ hb, float* __restrict__ as_, float* __restrict__ ad_,
    float* __restrict__ denom) {
  __shared__ float xsT[32][GR + 4];   // [k][row]
  __shared__ float ws[32][HDIM];      // [k][col]
  __shared__ float asl[GR], adl[GR];
  __shared__ float atts[HDIM], attd[HDIM];
  const int tid = threadIdx.x;
  const int row0 = blockIdx.x * GR;
  if (tid < GR) { asl[tid] = 0.f; adl[tid] = 0.f; }
  if (tid < 128) { atts[tid] = att_s[tid]; attd[tid] = att_d[tid]; }
  const int ty = tid >> 4;   // 0..15 -> 8 rows each
  const int tx = tid & 15;   // 0..15 -> 8 cols each
  float acc[8][8] = {};
  for (int kb = 0; kb < 4; ++kb) {
    __syncthreads();
    #pragma unroll
    for (int p = 0; p < 4; ++p) {   // x tile: 128 rows x 32 k, transposed store
      int idx = tid + p * 256;
      int r = idx >> 3, k4 = idx & 7;
      float4 v = *(const float4*)(x + (size_t)(row0 + r) * FDIM + kb * 32 + k4 * 4);
      xsT[k4 * 4 + 0][r] = v.x; xsT[k4 * 4 + 1][r] = v.y;
      xsT[k4 * 4 + 2][r] = v.z; xsT[k4 * 4 + 3][r] = v.w;
    }
    #pragma unroll
    for (int p = 0; p < 4; ++p) {   // W tile
      int kr = (tid >> 5) + p * 8;
      int c4 = (tid & 31) * 4;
      *(float4*)(&ws[kr][c4]) = *(const float4*)(W + (size_t)(kb * 32 + kr) * HDIM + c4);
    }
    __syncthreads();
    #pragma unroll
    for (int k = 0; k < 32; ++k) {
      float a[8], bb[8];
      *(float4*)&a[0]  = *(const float4*)(&xsT[k][ty * 8]);
      *(float4*)&a[4]  = *(const float4*)(&xsT[k][ty * 8 + 4]);
      *(float4*)&bb[0] = *(const float4*)(&ws[k][tx * 8]);
      *(float4*)&bb[4] = *(const float4*)(&ws[k][tx * 8 + 4]);
      #pragma unroll
      for (int i = 0; i < 8; ++i)
        #pragma unroll
        for (int j = 0; j < 8; ++j)
          acc[i][j] += a[i] * bb[j];
    }
  }
  float av[8], dv[8];
  *(float4*)&av[0] = *(const float4*)(&atts[tx * 8]);
  *(float4*)&av[4] = *(const float4*)(&atts[tx * 8 + 4]);
  *(float4*)&dv[0] = *(const float4*)(&attd[tx * 8]);
  *(float4*)&dv[4] = *(const float4*)(&attd[tx * 8 + 4]);
  #pragma unroll
  for (int i = 0; i < 8; ++i) {
    int row = row0 + ty * 8 + i;
    float ps = 0.f, pd = 0.f;
    #pragma unroll
    for (int j = 0; j < 8; ++j) { ps += acc[i][j] * av[j]; pd += acc[i][j] * dv[j]; }
    uint4 pk;
    pk.x = (unsigned int)f2bf(acc[i][0]) | ((unsigned int)f2bf(acc[i][1]) << 16);
    pk.y = (unsigned int)f2bf(acc[i][2]) | ((unsigned int)f2bf(acc[i][3]) << 16);
    pk.z = (unsigned int)f2bf(acc[i][4]) | ((unsigned int)f2bf(acc[i][5]) << 16);
    pk.w = (unsigned int)f2bf(acc[i][6]) | ((unsigned int)f2bf(acc[i][7]) << 16);
    *(uint4*)(hb + (size_t)row * HDIM + tx * 8) = pk;
    atomicAdd(&asl[ty * 8 + i], ps);
    atomicAdd(&adl[ty * 8 + i], pd);
  }
  __syncthreads();
  if (tid < GR) {
    float a = asl[tid], d = adl[tid];
    as_[row0 + tid] = a;
    ad_[row0 + tid] = d;
    denom[row0 + tid] = __expf(lrelu(a + d));   // self-loop seeds denominator
  }
}

// ---------------- edge-parallel softmax denominator
__global__ void k_denom(const int* __restrict__ ei, const float* __restrict__ as_,
                        const float* __restrict__ ad_, float* __restrict__ denom) {
  int g = blockIdx.x * 256 + threadIdx.x;   // T*E exact multiple
  int t = g / NEDGES, e = g - t * NEDGES;
  int src = ei[(size_t)t * 2 * NEDGES + e];
  int dst = ei[(size_t)t * 2 * NEDGES + NEDGES + e];
  float w = __expf(lrelu(as_[t * NNODES + src] + ad_[t * NNODES + dst]));
  atomicAdd(&denom[t * NNODES + dst], w);
}

// ---------------- dinv + self-loop coefficient (plain store: unique (t,n); runs
// after memset(c), before k_cbuild's atomics)
__global__ void k_selfdinv(const float* __restrict__ denom, const float* __restrict__ as_,
                           const float* __restrict__ ad_, const int* __restrict__ batch,
                           float* __restrict__ dinv, float* __restrict__ c) {
  int i = blockIdx.x * 256 + threadIdx.x;   // T*N exact multiple
  float inv = 1.0f / denom[i];
  dinv[i] = inv;
  int t = i / NNODES, n = i - t * NNODES;
  float wself = __expf(lrelu(as_[i] + ad_[i]));
  c[((size_t)t * BGR + batch[n]) * NNODES + n] = wself * inv;
}

// ---------------- edge-parallel coefficient build: c[t][batch[dst]][src] += alpha
__global__ void k_cbuild(const int* __restrict__ ei, const float* __restrict__ as_,
                         const float* __restrict__ ad_, const float* __restrict__ dinv,
                         const int* __restrict__ batch, float* __restrict__ c) {
  int g = blockIdx.x * 256 + threadIdx.x;   // T*E exact multiple
  int t = g / NEDGES, e = g - t * NEDGES;
  int src = ei[(size_t)t * 2 * NEDGES + e];
  int dst = ei[(size_t)t * 2 * NEDGES + NEDGES + e];
  int tn = t * NNODES + dst;
  float w = __expf(lrelu(as_[t * NNODES + src] + ad_[tn])) * dinv[tn];
  atomicAdd(&c[((size_t)t * BGR + batch[dst]) * NNODES + src], w);
}

// ---------------- batch segment starts (batch is sorted)
__global__ void k_starts(const int* __restrict__ batch, int* __restrict__ starts) {
  int n = blockIdx.x * 256 + threadIdx.x;
  if (n >= NNODES) return;
  int b = batch[n];
  if (n == 0) { for (int bb = 0; bb <= b; ++bb) starts[bb] = 0; }
  else { int pb = batch[n - 1]; for (int bb = pb + 1; bb <= b; ++bb) starts[bb] = n; }
  if (n == NNODES - 1) { for (int bb = b + 1; bb <= BGR; ++bb) starts[bb] = NNODES; }
}

// ---------------- pooled = c @ h : per (t, K-chunk) block computes a [64 x 128]
// partial over its 640 nodes; partials reduced in k_lstm_fc.
__global__ __launch_bounds__(256) void k_pgemm(
    const unsigned short* __restrict__ hb, const float* __restrict__ c,
    float* __restrict__ ppart) {
  __shared__ float cs[64][33];          // c tile [b][kk], pad -> conflict-free col reads
  __shared__ unsigned int hs[32][64];   // h tile [kk][d-pair]
  const int tid = threadIdx.x;
  const int t = blockIdx.x >> 5;        // / NCH
  const int ch = blockIdx.x & (NCH - 1);
  const int k0 = ch * KC;
  const int k1 = min(k0 + KC, NNODES);  // both multiples of 32
  const int bq = tid >> 4;              // b = bq*4 .. bq*4+3
  const int dq = tid & 15;              // d = dq*8 .. dq*8+7
  const float* cb = c + (size_t)t * BGR * NNODES;
  const unsigned short* hbase = hb + (size_t)t * NNODES * HDIM;
  float acc[4][8] = {};
  for (int kt = k0; kt < k1; kt += 32) {
    __syncthreads();
    #pragma unroll
    for (int p = 0; p < 2; ++p) {       // stage c: 64 b x 32 k
      int idx = tid + p * 256;          // 0..511
      int b = idx >> 3, q = idx & 7;
      float4 v = *(const float4*)(cb + (size_t)b * NNODES + kt + q * 4);
      cs[b][q * 4 + 0] = v.x; cs[b][q * 4 + 1] = v.y;
      cs[b][q * 4 + 2] = v.z; cs[b][q * 4 + 3] = v.w;
    }
    #pragma unroll
    for (int p = 0; p < 2; ++p) {       // stage h: 32 k x 128 d (bf16 pairs)
      int idx = tid + p * 256;          // 0..511
      int r = idx >> 4, slot = idx & 15;
      uint4 v = *(const uint4*)(hbase + (size_t)(kt + r) * HDIM + slot * 8);
      *(uint4*)(&hs[r][slot * 4]) = v;
    }
    __syncthreads();
    #pragma unroll
    for (int kk = 0; kk < 32; ++kk) {
      float cv[4];
      #pragma unroll
      for (int i = 0; i < 4; ++i) cv[i] = cs[bq * 4 + i][kk];
      unsigned int hu[4];
      #pragma unroll
      for (int q = 0; q < 4; ++q) hu[q] = hs[kk][dq * 4 + q];
      float hd[8];
      #pragma unroll
      for (int q = 0; q < 4; ++q) { hd[2 * q] = bf_lo(hu[q]); hd[2 * q + 1] = bf_hi(hu[q]); }
      #pragma unroll
      for (int i = 0; i < 4; ++i)
        #pragma unroll
        for (int d = 0; d < 8; ++d)
          acc[i][d] += cv[i] * hd[d];
    }
  }
  float* pp = ppart + ((size_t)t * NCH + ch) * BGR * HDIM;
  #pragma unroll
  for (int i = 0; i < 4; ++i) {
    *(float4*)(pp + (bq * 4 + i) * HDIM + dq * 8)     = make_float4(acc[i][0], acc[i][1], acc[i][2], acc[i][3]);
    *(float4*)(pp + (bq * 4 + i) * HDIM + dq * 8 + 4) = make_float4(acc[i][4], acc[i][5], acc[i][6], acc[i][7]);
  }
}

// ---------------- LSTM over T + fused FC (one block per batch row b)
// Chunk-partial reduce fused into the pooled load; gat_bias folded here.
// W_hh staged once into LDS as packed bf16 pairs (stride-65: conflict-free).
__global__ __launch_bounds__(512) void k_lstm_fc(
    const float* __restrict__ ppart, const int* __restrict__ starts,
    const float* __restrict__ gat_bias,
    const float* __restrict__ W_ih, const float* __restrict__ W_hh,
    const float* __restrict__ b_ih, const float* __restrict__ b_hh,
    const float* __restrict__ z, const float* __restrict__ fc_W,
    const float* __restrict__ fc_b, float* __restrict__ out) {
  const int b = blockIdx.x;
  const int g = threadIdx.x;   // gate index 0..511 (i,f,g,o blocks of 128)
  __shared__ unsigned int wpk[512 * 65];   // 133.1 KB packed bf16 W_hh
  __shared__ float hv[128], cv[128], part[512];
  __shared__ float pool8[TT][128];
  __shared__ float fcp[16][17];

  #pragma unroll 2
  for (int it = 0; it < 64; ++it) {
    int i = g + it * 512;
    int gr = i >> 6, j = i & 63;
    float2 wv = *(const float2*)(W_hh + (size_t)gr * HDIM + j * 2);
    wpk[gr * 65 + j] = (unsigned int)f2bf(wv.x) | ((unsigned int)f2bf(wv.y) << 16);
  }

  const int cntb = starts[b + 1] - starts[b];
  const float invc = 1.0f / (float)max(cntb, 1);
  #pragma unroll
  for (int i = 0; i < 2; ++i) {
    int idx = g + i * 512;
    int t = idx >> 7, k = idx & 127;
    const float* pp = ppart + ((size_t)t * NCH * BGR + b) * HDIM + k;
    float s = 0.f;
    #pragma unroll 8
    for (int ch = 0; ch < NCH; ++ch) s += pp[(size_t)ch * BGR * HDIM];
    pool8[t][k] = s * invc + gat_bias[k];
  }
  if (g < 128) { hv[g] = 0.f; cv[g] = 0.f; }
  __syncthreads();

  float gx[8] = {};
  {
    const float4* wi = (const float4*)(W_ih + (size_t)g * HDIM);
    #pragma unroll 2
    for (int k4 = 0; k4 < 32; ++k4) {
      float4 wv = wi[k4];
      #pragma unroll
      for (int t = 0; t < TT; ++t) {
        float4 p = *(const float4*)(&pool8[t][k4 * 4]);
        gx[t] += wv.x * p.x + wv.y * p.y + wv.z * p.z + wv.w * p.w;
      }
    }
  }
  const float bsum = b_ih[g] + b_hh[g];
  const unsigned int* wr = &wpk[g * 65];
  const float4* hv4 = (const float4*)hv;
  #pragma unroll
  for (int t = 0; t < TT; ++t) {
    float s = gx[t] + bsum;
    #pragma unroll 8
    for (int j2 = 0; j2 < 32; ++j2) {
      unsigned int w0 = wr[2 * j2], w1 = wr[2 * j2 + 1];
      float4 hh = hv4[j2];
      s += bf_lo(w0) * hh.x + bf_hi(w0) * hh.y + bf_lo(w1) * hh.z + bf_hi(w1) * hh.w;
    }
    part[g] = s;
    __syncthreads();
    if (g < 128) {
      float ig = sigmoidf(part[g]);
      float fg = sigmoidf(part[128 + g]);
      float gc = tanh_fast(part[256 + g]);
      float og = sigmoidf(part[384 + g]);
      float c = fg * cv[g] + ig * gc;
      cv[g] = c;
      hv[g] = og * tanh_fast(c);
    }
    __syncthreads();
  }
  if (g < 256) {
    const int c = g >> 4, kp = g & 15;
    float s = 0.f;
    for (int k = kp * 16; k < kp * 16 + 16; ++k) {
      float v = (k < 128) ? hv[k] : z[(size_t)b * HDIM + (k - 128)];
      s += v * fc_W[(size_t)c * 256 + k];
    }
    fcp[c][kp] = s;
  }
  __syncthreads();
  if (g < 16) {
    float r = fc_b[g];
    #pragma unroll
    for (int k = 0; k < 16; ++k) r += fcp[g][k];
    out[(size_t)b * NCLS + g] = r;
  }
}

extern "C" void kernel_launch(void* const* d_in, const int* in_sizes, int n_in,
                              void* d_out, int out_size, void* d_ws, size_t ws_size,
                              hipStream_t stream) {
  const float* x       = (const float*)d_in[0];
  const int*   ei      = (const int*)d_in[1];
  const int*   batch   = (const int*)d_in[2];
  const float* z       = (const float*)d_in[3];
  const float* gat_W   = (const float*)d_in[4];
  const float* att_src = (const float*)d_in[5];
  const float* att_dst = (const float*)d_in[6];
  const float* gat_bias= (const float*)d_in[7];
  const float* W_ih    = (const float*)d_in[8];
  const float* W_hh    = (const float*)d_in[9];
  const float* b_ih    = (const float*)d_in[10];
  const float* b_hh    = (const float*)d_in[11];
  const float* fc_W    = (const float*)d_in[12];
  const float* fc_b    = (const float*)d_in[13];
  float* out = (float*)d_out;

  char* ws = (char*)d_ws;
  size_t off = 0;
  auto alloc = [&](size_t bytes) {
    void* p = (void*)(ws + off);
    off += (bytes + 255) & ~(size_t)255;
    return p;
  };
  unsigned short* hbuf = (unsigned short*)alloc((size_t)TT * NNODES * HDIM * 2);    // 40.96 MB bf16
  float* as_    = (float*)alloc((size_t)TT * NNODES * 4);
  float* ad_    = (float*)alloc((size_t)TT * NNODES * 4);
  float* denom  = (float*)alloc((size_t)TT * NNODES * 4);
  float* dinv   = (float*)alloc((size_t)TT * NNODES * 4);
  float* cbuf   = (float*)alloc((size_t)TT * BGR * NNODES * 4);                     // 40.96 MB
  float* ppart  = (float*)alloc((size_t)TT * NCH * BGR * HDIM * 4);                 // 8.39 MB
  int*   starts = (int*)alloc((BGR + 1) * 4);
  (void)ws_size; (void)in_sizes; (void)n_in; (void)out_size;

  hipMemsetAsync(cbuf, 0, (size_t)TT * BGR * NNODES * 4, stream);

  k_gemm<<<(TT * NNODES) / GR, 256, 0, stream>>>(x, gat_W, att_src, att_dst, hbuf, as_, ad_, denom);
  k_denom<<<(TT * NEDGES) / 256, 256, 0, stream>>>(ei, as_, ad_, denom);
  k_selfdinv<<<(TT * NNODES) / 256, 256, 0, stream>>>(denom, as_, ad_, batch, dinv, cbuf);
  k_cbuild<<<(TT * NEDGES) / 256, 256, 0, stream>>>(ei, as_, ad_, dinv, batch, cbuf);
  k_starts<<<(NNODES + 255) / 256, 256, 0, stream>>>(batch, starts);
  k_pgemm<<<TT * NCH, 256, 0, stream>>>(hbuf, cbuf, ppart);
  k_lstm_fc<<<BGR, 512, 0, stream>>>(ppart, starts, gat_bias, W_ih, W_hh, b_ih, b_hh, z, fc_W, fc_b, out);
}

// Round 10
// 329.991 us; speedup vs baseline: 6.1816x; 1.4910x over previous
//
#include <hip/hip_runtime.h>
#include <math.h>

#define TT 8
#define NNODES 20000
#define NEDGES 320000
#define FDIM 128
#define HDIM 128
#define BGR 64
#define NCLS 16
#define GR 128    // gemm rows per block
#define NCH 32    // K-chunks per timestep for k_pgemm
#define KC 640    // nodes per chunk
#define NB 157    // radix buckets of 128 nodes (157*128 = 20096 >= 20000)
#define CB 80     // edge chunks per timestep
#define EC 4000   // edges per chunk (80*4000 = 320000)

__device__ __forceinline__ float lrelu(float x) { return fmaxf(x, 0.2f * x); }
__device__ __forceinline__ float sigmoidf(float x) { return 1.0f / (1.0f + __expf(-x)); }
__device__ __forceinline__ float tanh_fast(float x) {
  return 1.0f - 2.0f / (__expf(2.0f * x) + 1.0f);
}
__device__ __forceinline__ unsigned short f2bf(float f) {   // RNE
  unsigned int u = __float_as_uint(f);
  unsigned int r = (u + 0x7fff + ((u >> 16) & 1)) >> 16;
  return (unsigned short)r;
}
__device__ __forceinline__ float bf_lo(unsigned int u) { return __uint_as_float(u << 16); }
__device__ __forceinline__ float bf_hi(unsigned int u) { return __uint_as_float(u & 0xffff0000u); }

// ---------------- GEMM: h = x @ W (h stored bf16), epilogue: as, ad, denom seed (self term)
__global__ __launch_bounds__(256) void k_gemm(
    const float* __restrict__ x, const float* __restrict__ W,
    const float* __restrict__ att_s, const float* __restrict__ att_d,
    unsigned short* __restrict__ hb, float* __restrict__ as_, float* __restrict__ ad_,
    float* __restrict__ denom) {
  __shared__ float xsT[32][GR + 4];
  __shared__ float ws[32][HDIM];
  __shared__ float asl[GR], adl[GR];
  __shared__ float atts[HDIM], attd[HDIM];
  const int tid = threadIdx.x;
  const int row0 = blockIdx.x * GR;
  if (tid < GR) { asl[tid] = 0.f; adl[tid] = 0.f; }
  if (tid < 128) { atts[tid] = att_s[tid]; attd[tid] = att_d[tid]; }
  const int ty = tid >> 4;
  const int tx = tid & 15;
  float acc[8][8] = {};
  for (int kb = 0; kb < 4; ++kb) {
    __syncthreads();
    #pragma unroll
    for (int p = 0; p < 4; ++p) {
      int idx = tid + p * 256;
      int r = idx >> 3, k4 = idx & 7;
      float4 v = *(const float4*)(x + (size_t)(row0 + r) * FDIM + kb * 32 + k4 * 4);
      xsT[k4 * 4 + 0][r] = v.x; xsT[k4 * 4 + 1][r] = v.y;
      xsT[k4 * 4 + 2][r] = v.z; xsT[k4 * 4 + 3][r] = v.w;
    }
    #pragma unroll
    for (int p = 0; p < 4; ++p) {
      int kr = (tid >> 5) + p * 8;
      int c4 = (tid & 31) * 4;
      *(float4*)(&ws[kr][c4]) = *(const float4*)(W + (size_t)(kb * 32 + kr) * HDIM + c4);
    }
    __syncthreads();
    #pragma unroll
    for (int k = 0; k < 32; ++k) {
      float a[8], bb[8];
      *(float4*)&a[0]  = *(const float4*)(&xsT[k][ty * 8]);
      *(float4*)&a[4]  = *(const float4*)(&xsT[k][ty * 8 + 4]);
      *(float4*)&bb[0] = *(const float4*)(&ws[k][tx * 8]);
      *(float4*)&bb[4] = *(const float4*)(&ws[k][tx * 8 + 4]);
      #pragma unroll
      for (int i = 0; i < 8; ++i)
        #pragma unroll
        for (int j = 0; j < 8; ++j)
          acc[i][j] += a[i] * bb[j];
    }
  }
  float av[8], dv[8];
  *(float4*)&av[0] = *(const float4*)(&atts[tx * 8]);
  *(float4*)&av[4] = *(const float4*)(&atts[tx * 8 + 4]);
  *(float4*)&dv[0] = *(const float4*)(&attd[tx * 8]);
  *(float4*)&dv[4] = *(const float4*)(&attd[tx * 8 + 4]);
  #pragma unroll
  for (int i = 0; i < 8; ++i) {
    int row = row0 + ty * 8 + i;
    float ps = 0.f, pd = 0.f;
    #pragma unroll
    for (int j = 0; j < 8; ++j) { ps += acc[i][j] * av[j]; pd += acc[i][j] * dv[j]; }
    uint4 pk;
    pk.x = (unsigned int)f2bf(acc[i][0]) | ((unsigned int)f2bf(acc[i][1]) << 16);
    pk.y = (unsigned int)f2bf(acc[i][2]) | ((unsigned int)f2bf(acc[i][3]) << 16);
    pk.z = (unsigned int)f2bf(acc[i][4]) | ((unsigned int)f2bf(acc[i][5]) << 16);
    pk.w = (unsigned int)f2bf(acc[i][6]) | ((unsigned int)f2bf(acc[i][7]) << 16);
    *(uint4*)(hb + (size_t)row * HDIM + tx * 8) = pk;
    atomicAdd(&asl[ty * 8 + i], ps);
    atomicAdd(&adl[ty * 8 + i], pd);
  }
  __syncthreads();
  if (tid < GR) {
    float a = asl[tid], d = adl[tid];
    as_[row0 + tid] = a;
    ad_[row0 + tid] = d;
    denom[row0 + tid] = __expf(lrelu(a + d));   // self-loop seeds denominator
  }
}

// ---------------- radix pass A: per-(t,chunk) bucket histograms, keyed by dst AND src
__global__ __launch_bounds__(256) void k_pA(const int* __restrict__ ei,
                                            int* __restrict__ gcnt_d, int* __restrict__ gcnt_s) {
  __shared__ int hd[NB], hs[NB];
  const int tid = threadIdx.x;
  const int chunk = blockIdx.x, t = blockIdx.y;
  if (tid < NB) { hd[tid] = 0; hs[tid] = 0; }
  __syncthreads();
  const int* eis = ei + (size_t)t * 2 * NEDGES;
  for (int i = tid; i < EC; i += 256) {
    int e = chunk * EC + i;
    int s = eis[e], d = eis[NEDGES + e];
    atomicAdd(&hd[d >> 7], 1);
    atomicAdd(&hs[s >> 7], 1);
  }
  __syncthreads();
  if (tid < NB) {
    gcnt_d[((size_t)t * CB + chunk) * NB + tid] = hd[tid];
    gcnt_s[((size_t)t * CB + chunk) * NB + tid] = hs[tid];
  }
}

// ---------------- radix pass B: per-(t,axis) exclusive scan -> goff[t][bucket][chunk]
__global__ __launch_bounds__(256) void k_pB(const int* __restrict__ gcnt_d, const int* __restrict__ gcnt_s,
                                            int* __restrict__ goff_d, int* __restrict__ goff_s) {
  const int t = blockIdx.x >> 1, axis = blockIdx.x & 1;
  const int tid = threadIdx.x;
  const int* gc = axis ? gcnt_s : gcnt_d;
  int* go = axis ? goff_s : goff_d;
  __shared__ int tot[NB];
  __shared__ int base[NB];
  if (tid < NB) {
    int s = 0;
    for (int c = 0; c < CB; ++c) s += gc[((size_t)t * CB + c) * NB + tid];
    tot[tid] = s;
  }
  __syncthreads();
  if (tid == 0) {
    int run = 0;
    for (int B = 0; B < NB; ++B) { base[B] = run; run += tot[B]; }
  }
  __syncthreads();
  if (tid < NB) {
    int run = base[tid];
    for (int c = 0; c < CB; ++c) {
      go[((size_t)t * NB + tid) * CB + c] = run;
      run += gc[((size_t)t * CB + c) * NB + tid];
    }
  }
}

// ---------------- radix pass C: scatter packed records into both partitions (LDS cursors)
__global__ __launch_bounds__(256) void k_pC(const int* __restrict__ ei,
                                            const int* __restrict__ goff_d, const int* __restrict__ goff_s,
                                            unsigned int* __restrict__ part_d, unsigned int* __restrict__ part_s) {
  __shared__ int cd[NB], cs2[NB];
  const int tid = threadIdx.x;
  const int chunk = blockIdx.x, t = blockIdx.y;
  if (tid < NB) {
    cd[tid]  = goff_d[((size_t)t * NB + tid) * CB + chunk];
    cs2[tid] = goff_s[((size_t)t * NB + tid) * CB + chunk];
  }
  __syncthreads();
  const int* eis = ei + (size_t)t * 2 * NEDGES;
  unsigned int* pdt = part_d + (size_t)t * NEDGES;
  unsigned int* pst = part_s + (size_t)t * NEDGES;
  for (int i = tid; i < EC; i += 256) {
    int e = chunk * EC + i;
    int s = eis[e], d = eis[NEDGES + e];
    unsigned int rec = ((unsigned int)s << 15) | (unsigned int)d;
    int pd = atomicAdd(&cd[d >> 7], 1);
    pdt[pd] = rec;
    int ps = atomicAdd(&cs2[s >> 7], 1);
    pst[ps] = rec;
  }
}

// ---------------- denominator from dst-partition: LDS hist, plain-store flush
__global__ __launch_bounds__(256) void k_denomB(
    const unsigned int* __restrict__ part_d, const int* __restrict__ goff_d,
    const float* __restrict__ as_, const float* __restrict__ ad_, float* __restrict__ denom) {
  __shared__ float hist[128];
  __shared__ float adl[128];
  const int tid = threadIdx.x;
  const int B = blockIdx.x, t = blockIdx.y;
  if (tid < 128) {
    hist[tid] = 0.f;
    int n = B * 128 + tid;
    adl[tid] = (n < NNODES) ? ad_[t * NNODES + n] : 0.f;
  }
  __syncthreads();
  const int base = goff_d[((size_t)t * NB + B) * CB + 0];
  const int end  = (B + 1 < NB) ? goff_d[((size_t)t * NB + B + 1) * CB + 0] : NEDGES;
  const unsigned int* pdt = part_d + (size_t)t * NEDGES;
  const float* asb = as_ + (size_t)t * NNODES;
  for (int i = base + tid; i < end; i += 256) {
    unsigned int rec = pdt[i];
    int d = rec & 32767, s = rec >> 15;
    float w = __expf(lrelu(asb[s] + adl[d & 127]));
    atomicAdd(&hist[d & 127], w);
  }
  __syncthreads();
  if (tid < 128) {
    int n = B * 128 + tid;
    if (n < NNODES) denom[t * NNODES + n] += hist[tid];   // seed already there
  }
}

// ---------------- aux pack: (ad, 1/denom) per node
__global__ void k_dinvaux(const float* __restrict__ denom, const float* __restrict__ ad_,
                          float2* __restrict__ aux) {
  int i = blockIdx.x * 256 + threadIdx.x;   // T*N exact multiple of 256? 160000/256 = 625 exact
  aux[i] = make_float2(ad_[i], 1.0f / denom[i]);
}

// ---------------- batch segment starts (batch is sorted)
__global__ void k_starts(const int* __restrict__ batch, int* __restrict__ starts) {
  int n = blockIdx.x * 256 + threadIdx.x;
  if (n >= NNODES) return;
  int b = batch[n];
  if (n == 0) { for (int bb = 0; bb <= b; ++bb) starts[bb] = 0; }
  else { int pb = batch[n - 1]; for (int bb = pb + 1; bb <= b; ++bb) starts[bb] = n; }
  if (n == NNODES - 1) { for (int bb = b + 1; bb <= BGR; ++bb) starts[bb] = NNODES; }
}

// ---------------- c build from src-partition: LDS tile c_loc[64][128], plain-store flush
__global__ __launch_bounds__(256) void k_cbuildB(
    const unsigned int* __restrict__ part_s, const int* __restrict__ goff_s,
    const float* __restrict__ as_, const float2* __restrict__ aux,
    const int* __restrict__ batch, float* __restrict__ c) {
  __shared__ float cl[BGR * 128];   // 32 KB
  __shared__ float asl[128];
  const int tid = threadIdx.x;
  const int B = blockIdx.x, t = blockIdx.y;
  #pragma unroll
  for (int i = tid; i < BGR * 128; i += 256) cl[i] = 0.f;
  if (tid < 128) {
    int n = B * 128 + tid;
    asl[tid] = (n < NNODES) ? as_[t * NNODES + n] : 0.f;
  }
  __syncthreads();
  if (tid < 128) {   // self-loop coefficient (unique slot per thread; pre-edge, post-sync)
    int n = B * 128 + tid;
    if (n < NNODES) {
      float2 a2 = aux[t * NNODES + n];
      float wself = __expf(lrelu(asl[tid] + a2.x)) * a2.y;
      cl[batch[n] * 128 + tid] = wself;
    }
  }
  __syncthreads();
  const int base = goff_s[((size_t)t * NB + B) * CB + 0];
  const int end  = (B + 1 < NB) ? goff_s[((size_t)t * NB + B + 1) * CB + 0] : NEDGES;
  const unsigned int* pst = part_s + (size_t)t * NEDGES;
  const float2* auxt = aux + (size_t)t * NNODES;
  for (int i = base + tid; i < end; i += 256) {
    unsigned int rec = pst[i];
    int d = rec & 32767, s = rec >> 15;
    float2 a2 = auxt[d];
    float w = __expf(lrelu(asl[s & 127] + a2.x)) * a2.y;
    atomicAdd(&cl[batch[d] * 128 + (s & 127)], w);
  }
  __syncthreads();
  float* cb = c + (size_t)t * BGR * NNODES;
  #pragma unroll
  for (int idx = tid; idx < BGR * 128; idx += 256) {
    int b = idx >> 7, j = idx & 127;
    int col = B * 128 + j;
    if (col < NNODES) cb[(size_t)b * NNODES + col] = cl[idx];
  }
}

// ---------------- pooled = c @ h : per (t, K-chunk) block -> [64 x 128] partial
__global__ __launch_bounds__(256) void k_pgemm(
    const unsigned short* __restrict__ hb, const float* __restrict__ c,
    float* __restrict__ ppart) {
  __shared__ float cs[64][33];
  __shared__ unsigned int hs[32][64];
  const int tid = threadIdx.x;
  const int t = blockIdx.x >> 5;
  const int ch = blockIdx.x & (NCH - 1);
  const int k0 = ch * KC;
  const int k1 = min(k0 + KC, NNODES);
  const int bq = tid >> 4;
  const int dq = tid & 15;
  const float* cb = c + (size_t)t * BGR * NNODES;
  const unsigned short* hbase = hb + (size_t)t * NNODES * HDIM;
  float acc[4][8] = {};
  for (int kt = k0; kt < k1; kt += 32) {
    __syncthreads();
    #pragma unroll
    for (int p = 0; p < 2; ++p) {
      int idx = tid + p * 256;
      int b = idx >> 3, q = idx & 7;
      float4 v = *(const float4*)(cb + (size_t)b * NNODES + kt + q * 4);
      cs[b][q * 4 + 0] = v.x; cs[b][q * 4 + 1] = v.y;
      cs[b][q * 4 + 2] = v.z; cs[b][q * 4 + 3] = v.w;
    }
    #pragma unroll
    for (int p = 0; p < 2; ++p) {
      int idx = tid + p * 256;
      int r = idx >> 4, slot = idx & 15;
      uint4 v = *(const uint4*)(hbase + (size_t)(kt + r) * HDIM + slot * 8);
      *(uint4*)(&hs[r][slot * 4]) = v;
    }
    __syncthreads();
    #pragma unroll
    for (int kk = 0; kk < 32; ++kk) {
      float cv[4];
      #pragma unroll
      for (int i = 0; i < 4; ++i) cv[i] = cs[bq * 4 + i][kk];
      unsigned int hu[4];
      #pragma unroll
      for (int q = 0; q < 4; ++q) hu[q] = hs[kk][dq * 4 + q];
      float hd[8];
      #pragma unroll
      for (int q = 0; q < 4; ++q) { hd[2 * q] = bf_lo(hu[q]); hd[2 * q + 1] = bf_hi(hu[q]); }
      #pragma unroll
      for (int i = 0; i < 4; ++i)
        #pragma unroll
        for (int d = 0; d < 8; ++d)
          acc[i][d] += cv[i] * hd[d];
    }
  }
  float* pp = ppart + ((size_t)t * NCH + ch) * BGR * HDIM;
  #pragma unroll
  for (int i = 0; i < 4; ++i) {
    *(float4*)(pp + (bq * 4 + i) * HDIM + dq * 8)     = make_float4(acc[i][0], acc[i][1], acc[i][2], acc[i][3]);
    *(float4*)(pp + (bq * 4 + i) * HDIM + dq * 8 + 4) = make_float4(acc[i][4], acc[i][5], acc[i][6], acc[i][7]);
  }
}

// ---------------- LSTM over T + fused FC (one block per batch row b)
__global__ __launch_bounds__(512) void k_lstm_fc(
    const float* __restrict__ ppart, const int* __restrict__ starts,
    const float* __restrict__ gat_bias,
    const float* __restrict__ W_ih, const float* __restrict__ W_hh,
    const float* __restrict__ b_ih, const float* __restrict__ b_hh,
    const float* __restrict__ z, const float* __restrict__ fc_W,
    const float* __restrict__ fc_b, float* __restrict__ out) {
  const int b = blockIdx.x;
  const int g = threadIdx.x;
  __shared__ unsigned int wpk[512 * 65];
  __shared__ float hv[128], cv[128], part[512];
  __shared__ float pool8[TT][128];
  __shared__ float fcp[16][17];

  #pragma unroll 2
  for (int it = 0; it < 64; ++it) {
    int i = g + it * 512;
    int gr = i >> 6, j = i & 63;
    float2 wv = *(const float2*)(W_hh + (size_t)gr * HDIM + j * 2);
    wpk[gr * 65 + j] = (unsigned int)f2bf(wv.x) | ((unsigned int)f2bf(wv.y) << 16);
  }

  const int cntb = starts[b + 1] - starts[b];
  const float invc = 1.0f / (float)max(cntb, 1);
  #pragma unroll
  for (int i = 0; i < 2; ++i) {
    int idx = g + i * 512;
    int t = idx >> 7, k = idx & 127;
    const float* pp = ppart + ((size_t)t * NCH * BGR + b) * HDIM + k;
    float s = 0.f;
    #pragma unroll 8
    for (int ch = 0; ch < NCH; ++ch) s += pp[(size_t)ch * BGR * HDIM];
    pool8[t][k] = s * invc + gat_bias[k];
  }
  if (g < 128) { hv[g] = 0.f; cv[g] = 0.f; }
  __syncthreads();

  float gx[8] = {};
  {
    const float4* wi = (const float4*)(W_ih + (size_t)g * HDIM);
    #pragma unroll 2
    for (int k4 = 0; k4 < 32; ++k4) {
      float4 wv = wi[k4];
      #pragma unroll
      for (int t = 0; t < TT; ++t) {
        float4 p = *(const float4*)(&pool8[t][k4 * 4]);
        gx[t] += wv.x * p.x + wv.y * p.y + wv.z * p.z + wv.w * p.w;
      }
    }
  }
  const float bsum = b_ih[g] + b_hh[g];
  const unsigned int* wr = &wpk[g * 65];
  const float4* hv4 = (const float4*)hv;
  #pragma unroll
  for (int t = 0; t < TT; ++t) {
    float s = gx[t] + bsum;
    #pragma unroll 8
    for (int j2 = 0; j2 < 32; ++j2) {
      unsigned int w0 = wr[2 * j2], w1 = wr[2 * j2 + 1];
      float4 hh = hv4[j2];
      s += bf_lo(w0) * hh.x + bf_hi(w0) * hh.y + bf_lo(w1) * hh.z + bf_hi(w1) * hh.w;
    }
    part[g] = s;
    __syncthreads();
    if (g < 128) {
      float ig = sigmoidf(part[g]);
      float fg = sigmoidf(part[128 + g]);
      float gc = tanh_fast(part[256 + g]);
      float og = sigmoidf(part[384 + g]);
      float c = fg * cv[g] + ig * gc;
      cv[g] = c;
      hv[g] = og * tanh_fast(c);
    }
    __syncthreads();
  }
  if (g < 256) {
    const int c = g >> 4, kp = g & 15;
    float s = 0.f;
    for (int k = kp * 16; k < kp * 16 + 16; ++k) {
      float v = (k < 128) ? hv[k] : z[(size_t)b * HDIM + (k - 128)];
      s += v * fc_W[(size_t)c * 256 + k];
    }
    fcp[c][kp] = s;
  }
  __syncthreads();
  if (g < 16) {
    float r = fc_b[g];
    #pragma unroll
    for (int k = 0; k < 16; ++k) r += fcp[g][k];
    out[(size_t)b * NCLS + g] = r;
  }
}

extern "C" void kernel_launch(void* const* d_in, const int* in_sizes, int n_in,
                              void* d_out, int out_size, void* d_ws, size_t ws_size,
                              hipStream_t stream) {
  const float* x       = (const float*)d_in[0];
  const int*   ei      = (const int*)d_in[1];
  const int*   batch   = (const int*)d_in[2];
  const float* z       = (const float*)d_in[3];
  const float* gat_W   = (const float*)d_in[4];
  const float* att_src = (const float*)d_in[5];
  const float* att_dst = (const float*)d_in[6];
  const float* gat_bias= (const float*)d_in[7];
  const float* W_ih    = (const float*)d_in[8];
  const float* W_hh    = (const float*)d_in[9];
  const float* b_ih    = (const float*)d_in[10];
  const float* b_hh    = (const float*)d_in[11];
  const float* fc_W    = (const float*)d_in[12];
  const float* fc_b    = (const float*)d_in[13];
  float* out = (float*)d_out;

  char* ws = (char*)d_ws;
  size_t off = 0;
  auto alloc = [&](size_t bytes) {
    void* p = (void*)(ws + off);
    off += (bytes + 255) & ~(size_t)255;
    return p;
  };
  unsigned short* hbuf = (unsigned short*)alloc((size_t)TT * NNODES * HDIM * 2);  // 40.96 MB
  float*  as_    = (float*)alloc((size_t)TT * NNODES * 4);
  float*  ad_    = (float*)alloc((size_t)TT * NNODES * 4);
  float*  denom  = (float*)alloc((size_t)TT * NNODES * 4);
  float2* aux    = (float2*)alloc((size_t)TT * NNODES * 8);
  float*  cbuf   = (float*)alloc((size_t)TT * BGR * NNODES * 4);                  // 40.96 MB
  // partition region; ppart aliases its start (parts dead before k_pgemm writes)
  size_t parts_off = off;
  unsigned int* part_d = (unsigned int*)alloc((size_t)TT * NEDGES * 4);           // 10.24 MB
  unsigned int* part_s = (unsigned int*)alloc((size_t)TT * NEDGES * 4);           // 10.24 MB
  float* ppart = (float*)(ws + parts_off);
  int* gcnt_d = (int*)alloc((size_t)TT * CB * NB * 4);
  int* gcnt_s = (int*)alloc((size_t)TT * CB * NB * 4);
  int* goff_d = (int*)alloc((size_t)TT * NB * CB * 4);
  int* goff_s = (int*)alloc((size_t)TT * NB * CB * 4);
  int* starts = (int*)alloc((BGR + 1) * 4);
  (void)ws_size; (void)in_sizes; (void)n_in; (void)out_size;

  k_gemm<<<(TT * NNODES) / GR, 256, 0, stream>>>(x, gat_W, att_src, att_dst, hbuf, as_, ad_, denom);
  k_pA<<<dim3(CB, TT), 256, 0, stream>>>(ei, gcnt_d, gcnt_s);
  k_pB<<<TT * 2, 256, 0, stream>>>(gcnt_d, gcnt_s, goff_d, goff_s);
  k_pC<<<dim3(CB, TT), 256, 0, stream>>>(ei, goff_d, goff_s, part_d, part_s);
  k_denomB<<<dim3(NB, TT), 256, 0, stream>>>(part_d, goff_d, as_, ad_, denom);
  k_dinvaux<<<(TT * NNODES) / 256, 256, 0, stream>>>(denom, ad_, aux);
  k_starts<<<(NNODES + 255) / 256, 256, 0, stream>>>(batch, starts);
  k_cbuildB<<<dim3(NB, TT), 256, 0, stream>>>(part_s, goff_s, as_, aux, batch, cbuf);
  k_pgemm<<<TT * NCH, 256, 0, stream>>>(hbuf, cbuf, ppart);
  k_lstm_fc<<<BGR, 512, 0, stream>>>(ppart, starts, gat_bias, W_ih, W_hh, b_ih, b_hh, z, fc_W, fc_b, out);
}